// Round 3
// baseline (4312.025 us; speedup 1.0000x reference)
//
#include <hip/hip_runtime.h>

#define Bc 256
#define Tc 325
#define NSc 39
#define COc 64
#define NCc 20
#define ESc 117
#define ETc 648

// workspace layout in 4-byte units
#define WS_ROFF_S 0        // 40 ints
#define WS_EDGE_S 64       // 117 int2 (234 words)
#define WS_DINV_S 304      // 39 f
#define WS_ROFF_T 352      // 326 ints
#define WS_EDGE_T 680      // 648 int2 (1296 words)
#define WS_DINV_T 1976     // 325 f
#define WS_WT     2304     // 416000 f (tfc1_w transposed [20][20800])
#define WS_OUTS   418304   // 5120 f
#define WS_OUTT   423424   // 5120 f

// ---------------- prep: CSR (by dst, interleaved {src, nrm}) for both graphs ----------------
__global__ void prep_graph(const int* __restrict__ eiS, const int* __restrict__ eiT,
                           int* __restrict__ wsI, float* __restrict__ wsF) {
  const int which = blockIdx.x;
  const int* ei = which ? eiT : eiS;
  const int nE = which ? ETc : ESc;
  const int nN = which ? Tc : NSc;
  int* roff = wsI + (which ? WS_ROFF_T : WS_ROFF_S);
  int2* edge = (int2*)(wsI + (which ? WS_EDGE_T : WS_EDGE_S));
  float* dinv = wsF + (which ? WS_DINV_T : WS_DINV_S);
  const int* src = ei;
  const int* dst = ei + nE;
  for (int n = threadIdx.x; n < nN; n += blockDim.x) {
    int deg = 0, before = 0;
    for (int e = 0; e < nE; ++e) { deg += (dst[e] == n); before += (dst[e] < n); }
    roff[n] = before;
    if (n == nN - 1) roff[nN] = before + deg;
    dinv[n] = (deg > 0) ? (1.0f / sqrtf((float)deg)) : 0.0f;
  }
  __syncthreads();
  for (int n = threadIdx.x; n < nN; n += blockDim.x) {
    int cur = roff[n];
    float dn = dinv[n];
    for (int e = 0; e < nE; ++e) {
      if (dst[e] == n) {
        edge[cur] = make_int2(src[e], __float_as_int(dinv[src[e]] * dn));
        ++cur;
      }
    }
  }
}

// ---------------- prep: transpose tfc1_w [20800][20] -> [20][20800] ----------------
__global__ void prep_wt(const float* __restrict__ w, float* __restrict__ wT) {
  int i = blockIdx.x * 256 + threadIdx.x;
  if (i < NCc * Tc * COc) {
    int j = i / (Tc * COc);
    int p = i - j * (Tc * COc);
    wT[i] = w[p * NCc + j];
  }
}

// ---------------- fused: 1 batch per block (grid=256), spatial + interleaved temporal ----------------
__global__ __launch_bounds__(512, 2)
void lif_kernel(const float* __restrict__ data,
                const int* __restrict__ roffSg, const int2* __restrict__ edgeSg,
                const int* __restrict__ roffTg, const int2* __restrict__ edgeTg,
                const float* __restrict__ c1w, const float* __restrict__ c1b,
                const float* __restrict__ c2w, const float* __restrict__ c2b,
                const float* __restrict__ f1w, const float* __restrict__ f1b,
                const float* __restrict__ wT, const float* __restrict__ tf1b,
                float* __restrict__ outS, float* __restrict__ outT)
{
  __shared__ int roffS[NSc + 1];
  __shared__ int2 edgeS[ESc];
  __shared__ int roffT[Tc + 1];
  __shared__ int2 edgeT[ETc];
  __shared__ __align__(16) float featsS[NSc][20];
  __shared__ __align__(16) float featsT[Tc][20];
  __shared__ unsigned long long spkwT[Tc];
  __shared__ float redS[8][20];
  __shared__ float c2wL[16 * COc];

  const int tid = threadIdx.x;
  const int lane = tid & 63;
  const int wv = tid >> 6;
  const int b = blockIdx.x;

  // LDS init
  for (int i = tid; i < NSc + 1; i += 512) roffS[i] = roffSg[i];
  for (int i = tid; i < ESc; i += 512) edgeS[i] = edgeSg[i];
  for (int i = tid; i < Tc + 1; i += 512) roffT[i] = roffTg[i];
  for (int i = tid; i < ETc; i += 512) edgeT[i] = edgeTg[i];
  for (int i = tid; i < 16 * COc; i += 512) c2wL[i] = c2w[i];

  // resident registers
  float wc1[16];
#pragma unroll
  for (int r = 0; r < 16; ++r) wc1[r] = c1w[r * COc + lane];
  const float bcv1 = c1b[lane];
  const float bcv2 = c2b[lane];
  const float bS = (wv == 0 && lane < NCc) ? f1b[lane] : 0.0f;

  // spatial fc weights: wave wv owns nodes i = wv + 8q (q<5), all 20 outputs
  float wfc[100];
#pragma unroll
  for (int q = 0; q < 5; ++q) {
    int i = wv + 8 * q;
#pragma unroll
    for (int jj = 0; jj < 20; ++jj)
      wfc[q * 20 + jj] = (i < NSc) ? f1w[(i * COc + lane) * NCc + jj] : 0.0f;
  }

  // temporal fc: wave -> output group
  const int j0 = (wv < 4) ? wv * 3 : 12 + (wv - 4) * 2;
  const int jn = (wv < 4) ? 3 : 2;
  float bjT[3];
#pragma unroll
  for (int jj = 0; jj < 3; ++jj) bjT[jj] = (jj < jn) ? tf1b[j0 + jj] : 0.0f;
  const float* pw = wT + j0 * (Tc * COc) + lane;

  // states
  float cm[5] = {0, 0, 0, 0, 0};
  float hmS = 0.0f, hsumS = 0.0f;              // valid on wv==0, lane<20
  float tm[41];
#pragma unroll
  for (int q = 0; q < 41; ++q) tm[q] = 0.0f;
  float hmT[3] = {0, 0, 0}, hsumT[3] = {0, 0, 0};

  const float* dbase = data + (size_t)b * (2 * NSc * 2 * Tc);
  __syncthreads();

#pragma unroll 1
  for (int t = 0; t < Tc; ++t) {
    // ---- spatial hop phase (waves 0-3 = channel c) ----
    if (wv < 4) {
      const int c = wv;
      if (lane < NSc) {
        float h = dbase[((lane + (c >> 1) * NSc) * 2 + (c & 1)) * Tc + t];
        featsS[lane][c] = h;
      }
#pragma unroll
      for (int k = 1; k <= 3; ++k) {
        if (lane < NSc) {
          float v = 0.0f;
          int e0 = roffS[lane], e1 = roffS[lane + 1];
          for (int e = e0; e < e1; ++e) {
            int2 ed = edgeS[e];
            v = fmaf(__int_as_float(ed.y), featsS[ed.x][(k - 1) * 4 + c], v);
          }
          featsS[lane][k * 4 + c] = v;
        }
      }
    }
    __syncthreads();

    // ---- spatial conv + LIF + fc partial (ballot stays in-register) ----
    float p[20];
#pragma unroll
    for (int jj = 0; jj < 20; ++jj) p[jj] = 0.0f;
#pragma unroll
    for (int q = 0; q < 5; ++q) {
      int i = wv + 8 * q;
      if (i < NSc) {
        const float4* f4 = (const float4*)featsS[i];
        float fv[16];
        *(float4*)&fv[0] = f4[0];
        *(float4*)&fv[4] = f4[1];
        *(float4*)&fv[8] = f4[2];
        *(float4*)&fv[12] = f4[3];
        float acc = bcv1;
#pragma unroll
        for (int r = 0; r < 16; ++r) acc = fmaf(fv[r], wc1[r], acc);
        float old = cm[q];
        float m = (old * 0.2f) * ((old > 0.5f) ? 0.0f : 1.0f) + acc;
        cm[q] = m;
        unsigned long long wd = __ballot(m > 0.5f);
        float g = (float)((wd >> lane) & 1ull);
#pragma unroll
        for (int jj = 0; jj < 20; ++jj) p[jj] = fmaf(g, wfc[q * 20 + jj], p[jj]);
      }
    }
#pragma unroll
    for (int off = 32; off >= 1; off >>= 1)
#pragma unroll
      for (int jj = 0; jj < 20; ++jj)
        p[jj] += __shfl_xor(p[jj], off, 64);
    if (lane == 0) {
#pragma unroll
      for (int jj = 0; jj < 20; ++jj) redS[wv][jj] = p[jj];
    }
    __syncthreads();
    if (wv == 0 && lane < NCc) {
      float tot = bS;
#pragma unroll
      for (int ww = 0; ww < 8; ++ww) tot += redS[ww][lane];
      float old = hmS;
      float m = (old * 0.2f) * ((old > 0.5f) ? 0.0f : 1.0f) + tot;
      hmS = m;
      hsumS += (m > 0.5f) ? 1.0f : 0.0f;
    }

    // ---- temporal step every 8th t ----
    if ((t & 7) == 7 && (t >> 3) < NSc) {
      const int s = t >> 3;
      // stage x_s (coalesced in t)
#pragma unroll
      for (int k2 = 0; k2 < 3; ++k2) {
        int idx = tid + 512 * k2;
        if (idx < Tc * 4) {
          int c = idx / Tc, tt = idx - c * Tc;
          featsT[tt][c] = dbase[((s + (c >> 1) * NSc) * 2 + (c & 1)) * Tc + tt];
        }
      }
      __syncthreads();
#pragma unroll
      for (int k = 1; k <= 3; ++k) {
#pragma unroll
        for (int k2 = 0; k2 < 3; ++k2) {
          int idx = tid + 512 * k2;
          if (idx < Tc * 4) {
            int tt = idx >> 2, c = idx & 3;
            float v = 0.0f;
            int e0 = roffT[tt], e1 = roffT[tt + 1];
            for (int e = e0; e < e1; ++e) {
              int2 ed = edgeT[e];
              v = fmaf(__int_as_float(ed.y), featsT[ed.x][(k - 1) * 4 + c], v);
            }
            featsT[tt][k * 4 + c] = v;
          }
        }
        __syncthreads();
      }
      // conv + LIF (wc2 reloaded per step -> short live range)
      float wc2[16];
#pragma unroll
      for (int r = 0; r < 16; ++r) wc2[r] = c2wL[r * COc + lane];
#pragma unroll
      for (int q = 0; q < 41; ++q) {
        int i = wv + 8 * q;
        if (i < Tc) {
          const float4* f4 = (const float4*)featsT[i];
          float fv[16];
          *(float4*)&fv[0] = f4[0];
          *(float4*)&fv[4] = f4[1];
          *(float4*)&fv[8] = f4[2];
          *(float4*)&fv[12] = f4[3];
          float acc = bcv2;
#pragma unroll
          for (int r = 0; r < 16; ++r) acc = fmaf(fv[r], wc2[r], acc);
          float old = tm[q];
          float m = (old * 0.2f) * ((old > 0.5f) ? 0.0f : 1.0f) + acc;
          tm[q] = m;
          unsigned long long wd = __ballot(m > 0.5f);
          if (lane == 0) spkwT[i] = wd;
        }
      }
      __syncthreads();
      // fc: stream wT from L2 with spike-sparsity skip
      float a0 = 0.0f, a1 = 0.0f, a2 = 0.0f;
      if (jn == 3) {
        for (int i = 0; i < Tc; ++i) {
          unsigned long long wd = spkwT[i];
          if (wd) {
            if ((wd >> lane) & 1ull) {
              a0 += pw[i * COc];
              a1 += pw[Tc * COc + i * COc];
              a2 += pw[2 * Tc * COc + i * COc];
            }
          }
        }
      } else {
        for (int i = 0; i < Tc; ++i) {
          unsigned long long wd = spkwT[i];
          if (wd) {
            if ((wd >> lane) & 1ull) {
              a0 += pw[i * COc];
              a1 += pw[Tc * COc + i * COc];
            }
          }
        }
      }
#pragma unroll
      for (int off = 32; off >= 1; off >>= 1) {
        a0 += __shfl_xor(a0, off, 64);
        a1 += __shfl_xor(a1, off, 64);
        a2 += __shfl_xor(a2, off, 64);
      }
      float av[3] = {a0, a1, a2};
#pragma unroll
      for (int jj = 0; jj < 3; ++jj) {
        if (jj < jn) {
          float m = hmT[jj];
          m = (m * 0.2f) * ((m > 0.5f) ? 0.0f : 1.0f) + av[jj] + bjT[jj];
          hmT[jj] = m;
          hsumT[jj] += (m > 0.5f) ? 1.0f : 0.0f;
        }
      }
    }
  }

  if (wv == 0 && lane < NCc) outS[b * NCc + lane] = hsumS / (float)Tc;
  if (lane == 0) {
    for (int jj = 0; jj < jn; ++jj)
      outT[b * NCc + j0 + jj] = hsumT[jj] / (float)NSc;
  }
}

__global__ void combine_kernel(const float* __restrict__ a, const float* __restrict__ c,
                               float* __restrict__ o) {
  int i = blockIdx.x * 256 + threadIdx.x;
  if (i < Bc * NCc) o[i] = (a[i] + c[i]) * 0.5f;
}

extern "C" void kernel_launch(void* const* d_in, const int* in_sizes, int n_in,
                              void* d_out, int out_size, void* d_ws, size_t ws_size,
                              hipStream_t stream) {
  const float* data = (const float*)d_in[0];
  const int*   eiS  = (const int*)d_in[1];
  const int*   eiT  = (const int*)d_in[2];
  const float* c1w  = (const float*)d_in[3];
  const float* c1b  = (const float*)d_in[4];
  const float* c2w  = (const float*)d_in[5];
  const float* c2b  = (const float*)d_in[6];
  const float* f1w  = (const float*)d_in[7];
  const float* f1b  = (const float*)d_in[8];
  const float* tf1w = (const float*)d_in[9];
  const float* tf1b = (const float*)d_in[10];
  float* out = (float*)d_out;
  int* wsI = (int*)d_ws;
  float* wsF = (float*)d_ws;

  prep_graph<<<2, 256, 0, stream>>>(eiS, eiT, wsI, wsF);
  prep_wt<<<(NCc * Tc * COc + 255) / 256, 256, 0, stream>>>(tf1w, wsF + WS_WT);
  lif_kernel<<<Bc, 512, 0, stream>>>(data,
                                     wsI + WS_ROFF_S, (const int2*)(wsI + WS_EDGE_S),
                                     wsI + WS_ROFF_T, (const int2*)(wsI + WS_EDGE_T),
                                     c1w, c1b, c2w, c2b, f1w, f1b,
                                     wsF + WS_WT, tf1b,
                                     wsF + WS_OUTS, wsF + WS_OUTT);
  combine_kernel<<<(Bc * NCc + 255) / 256, 256, 0, stream>>>(wsF + WS_OUTS,
                                                             wsF + WS_OUTT, out);
}